// Round 1
// baseline (97.716 us; speedup 1.0000x reference)
//
#include <hip/hip_runtime.h>
#include <hip/hip_bf16.h>

#define B_ 32
#define PRE_ 2048
#define POST_ 2048

typedef __attribute__((ext_vector_type(8))) short short8;
typedef __attribute__((ext_vector_type(4))) float floatx4;

__device__ __forceinline__ unsigned short f2bf(float f) {
    unsigned u = __float_as_uint(f);
    u += 0x7FFF + ((u >> 16) & 1);   // round-to-nearest-even
    return (unsigned short)(u >> 16);
}
__device__ __forceinline__ float bf2f(unsigned short h) {
    return __uint_as_float(((unsigned)h) << 16);
}

// ws layout (unsigned short elements):
//   spT  [POST][B]  @ 0        spike^T, bf16 (exact: 0/1)
//   ntqh [POST][B]  @ 65536    hi(-tq)
//   ntql [POST][B]  @ 131072   lo(-tq)
//   tphT [PRE][B]   @ 196608   hi(tp)
//   tplT [PRE][B]   @ 262144   lo(tp)
//   xT   [PRE][B]   @ 327680   x, bf16 (exact: 0/1)

// Kernel A: blocks 0..127: i = x @ W^T (split-bf16 MFMA, K-split over 4 waves),
//           spike -> d_out, spike^T / -tq^T bf16 frags -> ws.
//           blocks 128..191: elementwise tp prep -> ws.
__global__ __launch_bounds__(256) void stdp_kernelA(
    const float* __restrict__ x, const float* __restrict__ W,
    const float* __restrict__ trace_pre, const float* __restrict__ trace_post,
    float* __restrict__ out, unsigned short* __restrict__ ws)
{
    unsigned short* spT  = ws;
    unsigned short* ntqh = ws + 65536;
    unsigned short* ntql = ws + 2 * 65536;
    unsigned short* tphT = ws + 3 * 65536;
    unsigned short* tplT = ws + 4 * 65536;
    unsigned short* xT   = ws + 5 * 65536;

    const int tid = threadIdx.x;
    const int bid = blockIdx.x;

    if (bid >= 128) {
        // ---- elementwise prep: tp = 0.5*trace_pre + x, store transposed bf16 hi/lo + x^T ----
        int lin  = (bid - 128) * 256 + tid;   // 0..16383
        int base = lin * 4;                   // element index in [B, PRE]
        int b = base >> 11, p = base & 2047;
        floatx4 xv = *(const floatx4*)(x + base);
        floatx4 tv = *(const floatx4*)(trace_pre + base);
#pragma unroll
        for (int j = 0; j < 4; ++j) {
            float tp = 0.5f * tv[j] + xv[j];
            unsigned short h = f2bf(tp);
            unsigned short l = f2bf(tp - bf2f(h));
            int o = (p + j) * B_ + b;
            tphT[o] = h; tplT[o] = l; xT[o] = f2bf(xv[j]);
        }
        return;
    }

    // ---- GEMM part: q_tile = 16 rows of W per WG ----
    __shared__ unsigned short Wh[16][264];   // +8 pad: frag-read 2-way banks (free)
    __shared__ unsigned short Wl[16][264];
    __shared__ float red[4 * 2 * 4 * 64];    // 4 waves x 2 Mtiles x 4 regs x 64 lanes

    const int q0   = bid * 16;
    const int wave = tid >> 6, lane = tid & 63;
    const int quad = lane >> 4, l16 = lane & 15;

    floatx4 acc0 = {0.f, 0.f, 0.f, 0.f};
    floatx4 acc1 = {0.f, 0.f, 0.f, 0.f};

    for (int k0 = 0; k0 < PRE_; k0 += 256) {
        // stage W[q0:q0+16][k0:k0+256] as bf16 hi/lo into LDS
#pragma unroll
        for (int i = 0; i < 4; ++i) {
            int id = tid + i * 256;
            int r = id >> 6, c = (id & 63) << 2;
            floatx4 wv = *(const floatx4*)(W + (q0 + r) * PRE_ + k0 + c);
#pragma unroll
            for (int j = 0; j < 4; ++j) {
                unsigned short h = f2bf(wv[j]);
                Wh[r][c + j] = h;
                Wl[r][c + j] = f2bf(wv[j] - bf2f(h));
            }
        }
        __syncthreads();
        // each wave covers 2 of the 8 k-steps in this chunk (K-split partial sums)
#pragma unroll
        for (int t = 0; t < 2; ++t) {
            int koff = (wave * 2 + t) * 32 + quad * 8;
            short8 bh = *(const short8*)&Wh[l16][koff];
            short8 bl = *(const short8*)&Wl[l16][koff];
            int kk = k0 + koff;
            const float* xp0 = x + l16 * PRE_ + kk;
            const float* xp1 = x + (16 + l16) * PRE_ + kk;
            floatx4 x0a = *(const floatx4*)xp0;
            floatx4 x0b = *(const floatx4*)(xp0 + 4);
            floatx4 x1a = *(const floatx4*)xp1;
            floatx4 x1b = *(const floatx4*)(xp1 + 4);
            short8 a0, a1;
#pragma unroll
            for (int j = 0; j < 4; ++j) {
                a0[j]     = (short)f2bf(x0a[j]);
                a0[j + 4] = (short)f2bf(x0b[j]);
                a1[j]     = (short)f2bf(x1a[j]);
                a1[j + 4] = (short)f2bf(x1b[j]);
            }
            acc0 = __builtin_amdgcn_mfma_f32_16x16x32_bf16(a0, bh, acc0, 0, 0, 0);
            acc0 = __builtin_amdgcn_mfma_f32_16x16x32_bf16(a0, bl, acc0, 0, 0, 0);
            acc1 = __builtin_amdgcn_mfma_f32_16x16x32_bf16(a1, bh, acc1, 0, 0, 0);
            acc1 = __builtin_amdgcn_mfma_f32_16x16x32_bf16(a1, bl, acc1, 0, 0, 0);
        }
        __syncthreads();
    }

    // cross-wave K reduction via LDS
#pragma unroll
    for (int r = 0; r < 4; ++r) {
        red[((wave * 2 + 0) * 4 + r) * 64 + lane] = acc0[r];
        red[((wave * 2 + 1) * 4 + r) * 64 + lane] = acc1[r];
    }
    __syncthreads();

    if (wave == 0) {
        // D layout: col(q)=lane&15, row(b)=quad*4+reg (+16 for Mtile 1)
#pragma unroll
        for (int mt = 0; mt < 2; ++mt) {
#pragma unroll
            for (int r = 0; r < 4; ++r) {
                float s = 0.f;
#pragma unroll
                for (int w = 0; w < 4; ++w) s += red[((w * 2 + mt) * 4 + r) * 64 + lane];
                int b = mt * 16 + quad * 4 + r;
                int q = q0 + l16;
                float spike = (s >= 1.0f) ? 1.0f : 0.0f;
                out[b * POST_ + q] = spike;
                float tq = 0.5f * trace_post[b * POST_ + q] + spike;
                unsigned short h = f2bf(-tq);
                unsigned short l = f2bf(-tq - bf2f(h));
                int o = q * B_ + b;
                spT[o]  = f2bf(spike);
                ntqh[o] = h;
                ntql[o] = l;
            }
        }
    }
}

// Kernel B: dw = clip(W,±1) * (spike^T @ tp - tq^T @ x), K=32 -> 4 MFMAs/tile.
// WG tile 64q x 64p; wave w owns p-range w*16; 4 q-subtiles per wave.
__global__ __launch_bounds__(256) void stdp_kernelB(
    const float* __restrict__ W, const unsigned short* __restrict__ ws,
    float* __restrict__ out)
{
    const unsigned short* spT  = ws;
    const unsigned short* ntqh = ws + 65536;
    const unsigned short* ntql = ws + 2 * 65536;
    const unsigned short* tphT = ws + 3 * 65536;
    const unsigned short* tplT = ws + 4 * 65536;
    const unsigned short* xT   = ws + 5 * 65536;
    float* dw = out + B_ * POST_;

    const int tid  = threadIdx.x;
    const int wave = tid >> 6, lane = tid & 63;
    const int quad = lane >> 4, l16 = lane & 15;
    const int qb = blockIdx.x >> 5, pb = blockIdx.x & 31;
    const int q0 = qb * 64, p0 = pb * 64;

    const int pw = p0 + wave * 16 + l16;
    // B-operand frags: B[k=b][n=p], lane n=l16, k=quad*8+j  (stored transposed [p][b])
    short8 fx  = *(const short8*)(xT   + pw * B_ + quad * 8);
    short8 fth = *(const short8*)(tphT + pw * B_ + quad * 8);
    short8 ftl = *(const short8*)(tplT + pw * B_ + quad * 8);

#pragma unroll
    for (int qt = 0; qt < 4; ++qt) {
        int q = q0 + qt * 16 + l16;
        // A-operand frags: A[m=q][k=b], lane m=l16, k=quad*8+j
        short8 fs  = *(const short8*)(spT  + q * B_ + quad * 8);
        short8 fnh = *(const short8*)(ntqh + q * B_ + quad * 8);
        short8 fnl = *(const short8*)(ntql + q * B_ + quad * 8);
        floatx4 acc = {0.f, 0.f, 0.f, 0.f};
        acc = __builtin_amdgcn_mfma_f32_16x16x32_bf16(fs,  fth, acc, 0, 0, 0);
        acc = __builtin_amdgcn_mfma_f32_16x16x32_bf16(fs,  ftl, acc, 0, 0, 0);
        acc = __builtin_amdgcn_mfma_f32_16x16x32_bf16(fnh, fx,  acc, 0, 0, 0);
        acc = __builtin_amdgcn_mfma_f32_16x16x32_bf16(fnl, fx,  acc, 0, 0, 0);
        // D layout: col(p)=l16, row(q)=quad*4+reg
#pragma unroll
        for (int r = 0; r < 4; ++r) {
            int qq = q0 + qt * 16 + quad * 4 + r;
            float wv = W[qq * PRE_ + pw];
            wv = fminf(fmaxf(wv, -1.0f), 1.0f);
            dw[qq * PRE_ + pw] = wv * acc[r];
        }
    }
}

extern "C" void kernel_launch(void* const* d_in, const int* in_sizes, int n_in,
                              void* d_out, int out_size, void* d_ws, size_t ws_size,
                              hipStream_t stream) {
    const float* x     = (const float*)d_in[0];
    const float* W     = (const float*)d_in[1];
    const float* tpre  = (const float*)d_in[2];
    const float* tpost = (const float*)d_in[3];
    float* out = (float*)d_out;
    unsigned short* ws = (unsigned short*)d_ws;

    hipLaunchKernelGGL(stdp_kernelA, dim3(192), dim3(256), 0, stream,
                       x, W, tpre, tpost, out, ws);
    hipLaunchKernelGGL(stdp_kernelB, dim3(1024), dim3(256), 0, stream,
                       W, ws, out);
}

// Round 2
// 93.761 us; speedup vs baseline: 1.0422x; 1.0422x over previous
//
#include <hip/hip_runtime.h>

#define B_ 32
#define PRE_ 2048
#define POST_ 2048
#define QT 8            // q rows per WG in fused kernel
#define WPAD 2056       // LDS row stride (elements) for W tiles

typedef __attribute__((ext_vector_type(8))) short short8;
typedef __attribute__((ext_vector_type(4))) short short4v;
typedef __attribute__((ext_vector_type(4))) float floatx4;

__device__ __forceinline__ unsigned short f2bf(float f) {
    unsigned u = __float_as_uint(f);
    u += 0x7FFF + ((u >> 16) & 1);   // round-to-nearest-even
    return (unsigned short)(u >> 16);
}
__device__ __forceinline__ float bf2f(unsigned short h) {
    return __uint_as_float(((unsigned)h) << 16);
}

// ws layout (unsigned short elements):
//   xrow [32][2048]  @ 0        x row-major bf16 (exact 0/1) - forward A-frags
//   tpTh [2048][32]  @ 65536    hi(tp),  tp = 0.5*trace_pre + x
//   tpTl [2048][32]  @ 131072   lo(tp)
//   xT   [2048][32]  @ 196608   x^T bf16 (exact 0/1) - dw B-frags

__global__ __launch_bounds__(256) void stdp_prep(
    const float* __restrict__ x, const float* __restrict__ trace_pre,
    unsigned short* __restrict__ ws)
{
    int lin  = blockIdx.x * 256 + threadIdx.x;   // 0..16383
    int base = lin * 4;                          // element index in [B, PRE]
    int b = base >> 11, p = base & 2047;
    floatx4 xv = *(const floatx4*)(x + base);
    floatx4 tv = *(const floatx4*)(trace_pre + base);
    short4v xr;
#pragma unroll
    for (int j = 0; j < 4; ++j) {
        float tp = 0.5f * tv[j] + xv[j];
        unsigned short h = f2bf(tp);
        unsigned short l = f2bf(tp - bf2f(h));
        int o = (p + j) * B_ + b;
        ws[65536 + o]     = h;           // tpTh
        ws[2 * 65536 + o] = l;           // tpTl
        ws[3 * 65536 + o] = f2bf(xv[j]); // xT
        xr[j] = (short)f2bf(xv[j]);
    }
    *(short4v*)(ws + base) = xr;         // xrow, coalesced 8B store
}

// Fused: per WG of 8 q-rows -- forward i = x @ W^T (split-bf16 MFMA),
// spike -> out, then dw for the same rows with W reused from LDS.
__global__ __launch_bounds__(512) void stdp_fused(
    const float* __restrict__ W, const float* __restrict__ trace_post,
    const unsigned short* __restrict__ ws, float* __restrict__ out)
{
    __shared__ __align__(16) unsigned short Wh[QT * WPAD];   // 32.9 KB
    __shared__ __align__(16) unsigned short Wl[QT * WPAD];   // 32.9 KB
    __shared__ __align__(16) float red[8 * 2 * 4 * 64];      // 16 KB
    __shared__ __align__(16) unsigned short spA[QT * 32];    // A-frags for dw
    __shared__ __align__(16) unsigned short nqh[QT * 32];
    __shared__ __align__(16) unsigned short nql[QT * 32];

    const int tid  = threadIdx.x;
    const int wave = tid >> 6, lane = tid & 63;
    const int quad = lane >> 4, l16 = lane & 15;
    const int q0   = blockIdx.x * QT;
    const int qb   = l16 & 7;            // clamped q row (8 valid of 16)

    // ---- stage W[q0:q0+8][0:2048] -> LDS bf16 hi/lo (W touches HBM once) ----
#pragma unroll
    for (int it = 0; it < 8; ++it) {
        int id = tid + it * 512;         // 0..4095
        int r  = id >> 9;                // row 0..7
        int c  = (id & 511) << 2;        // col
        floatx4 wv = *(const floatx4*)(W + (q0 + r) * PRE_ + c);
#pragma unroll
        for (int j = 0; j < 4; ++j) {
            unsigned short h = f2bf(wv[j]);
            Wh[r * WPAD + c + j] = h;
            Wl[r * WPAD + c + j] = f2bf(wv[j] - bf2f(h));
        }
    }
    __syncthreads();

    // ---- forward: i[32 x 8] = x @ Wtile^T, K=2048 split across 8 waves ----
    const unsigned short* xrow = ws;
    floatx4 acc0 = {0.f, 0.f, 0.f, 0.f};
    floatx4 acc1 = {0.f, 0.f, 0.f, 0.f};
#pragma unroll
    for (int s = 0; s < 8; ++s) {
        int ko = wave * 256 + s * 32 + quad * 8;
        short8 a0 = *(const short8*)(xrow + l16 * PRE_ + ko);        // b = l16
        short8 a1 = *(const short8*)(xrow + (16 + l16) * PRE_ + ko); // b = 16+l16
        short8 bh = *(const short8*)(Wh + qb * WPAD + ko);
        short8 bl = *(const short8*)(Wl + qb * WPAD + ko);
        acc0 = __builtin_amdgcn_mfma_f32_16x16x32_bf16(a0, bh, acc0, 0, 0, 0);
        acc0 = __builtin_amdgcn_mfma_f32_16x16x32_bf16(a0, bl, acc0, 0, 0, 0);
        acc1 = __builtin_amdgcn_mfma_f32_16x16x32_bf16(a1, bh, acc1, 0, 0, 0);
        acc1 = __builtin_amdgcn_mfma_f32_16x16x32_bf16(a1, bl, acc1, 0, 0, 0);
    }
#pragma unroll
    for (int r = 0; r < 4; ++r) {
        red[((wave * 2 + 0) * 4 + r) * 64 + lane] = acc0[r];
        red[((wave * 2 + 1) * 4 + r) * 64 + lane] = acc1[r];
    }
    __syncthreads();

    // ---- reduce + spike + tq: waves 0/1 handle M-tiles 0/1 ----
    if (wave < 2 && l16 < QT) {
        int mt = wave;
        int q  = q0 + l16;
#pragma unroll
        for (int r = 0; r < 4; ++r) {
            float s = 0.f;
#pragma unroll
            for (int w = 0; w < 8; ++w) s += red[((w * 2 + mt) * 4 + r) * 64 + lane];
            int b = mt * 16 + quad * 4 + r;
            float spike = (s >= 1.0f) ? 1.0f : 0.0f;
            out[b * POST_ + q] = spike;
            float ntq = -(0.5f * trace_post[b * POST_ + q] + spike);
            unsigned short h = f2bf(ntq);
            unsigned short l = f2bf(ntq - bf2f(h));
            spA[l16 * 32 + b] = f2bf(spike);
            nqh[l16 * 32 + b] = h;
            nql[l16 * 32 + b] = l;
        }
    }
    __syncthreads();

    // ---- dw: D[16q x 16p] tiles, K=32 -> 4 MFMAs; W from LDS ----
    const unsigned short* tpTh = ws + 65536;
    const unsigned short* tpTl = ws + 2 * 65536;
    const unsigned short* xT   = ws + 3 * 65536;
    float* dw = out + B_ * POST_;

    // A-frags constant across p-tiles: hoist (A[m=q][k=b], lane m=l16)
    short8 fs  = *(const short8*)(spA + qb * 32 + quad * 8);
    short8 fnh = *(const short8*)(nqh + qb * 32 + quad * 8);
    short8 fnl = *(const short8*)(nql + qb * 32 + quad * 8);

#pragma unroll 2
    for (int it = 0; it < 16; ++it) {
        int p0 = (wave * 16 + it) * 16;
        int p  = p0 + l16;
        // B-frags: B[k=b][n=p], stored transposed [p][b] -> fully coalesced 16B/lane
        short8 fth = *(const short8*)(tpTh + p * 32 + quad * 8);
        short8 ftl = *(const short8*)(tpTl + p * 32 + quad * 8);
        short8 fx  = *(const short8*)(xT   + p * 32 + quad * 8);
        floatx4 acc = {0.f, 0.f, 0.f, 0.f};
        acc = __builtin_amdgcn_mfma_f32_16x16x32_bf16(fs,  fth, acc, 0, 0, 0);
        acc = __builtin_amdgcn_mfma_f32_16x16x32_bf16(fs,  ftl, acc, 0, 0, 0);
        acc = __builtin_amdgcn_mfma_f32_16x16x32_bf16(fnh, fx,  acc, 0, 0, 0);
        acc = __builtin_amdgcn_mfma_f32_16x16x32_bf16(fnl, fx,  acc, 0, 0, 0);
        // D: col(p)=l16, row(q)=quad*4+r ; only rows 0..7 valid (quads 0,1)
        if (quad < 2) {
#pragma unroll
            for (int r = 0; r < 4; ++r) {
                int qd = quad * 4 + r;
                float wv = bf2f(Wh[qd * WPAD + p]) + bf2f(Wl[qd * WPAD + p]);
                wv = fminf(fmaxf(wv, -1.0f), 1.0f);
                dw[(q0 + qd) * PRE_ + p] = wv * acc[r];
            }
        }
    }
}

extern "C" void kernel_launch(void* const* d_in, const int* in_sizes, int n_in,
                              void* d_out, int out_size, void* d_ws, size_t ws_size,
                              hipStream_t stream) {
    const float* x     = (const float*)d_in[0];
    const float* W     = (const float*)d_in[1];
    const float* tpre  = (const float*)d_in[2];
    const float* tpost = (const float*)d_in[3];
    float* out = (float*)d_out;
    unsigned short* ws = (unsigned short*)d_ws;

    hipLaunchKernelGGL(stdp_prep, dim3(64), dim3(256), 0, stream, x, tpre, ws);
    hipLaunchKernelGGL(stdp_fused, dim3(POST_ / QT / 1), dim3(512), 0, stream,
                       W, tpost, ws, out);
}

// Round 3
// 92.533 us; speedup vs baseline: 1.0560x; 1.0133x over previous
//
#include <hip/hip_runtime.h>

#define B_ 32
#define PRE_ 2048
#define POST_ 2048
#define QT 8            // q rows per WG in fused kernel
#define WPAD 2056       // LDS row stride (shorts); 2056*2B = 16B-multiple

typedef __attribute__((ext_vector_type(8))) short short8;
typedef __attribute__((ext_vector_type(4))) short short4v;
typedef __attribute__((ext_vector_type(4))) float floatx4;

__device__ __forceinline__ unsigned short f2bf(float f) {
    unsigned u = __float_as_uint(f);
    u += 0x7FFF + ((u >> 16) & 1);   // round-to-nearest-even
    return (unsigned short)(u >> 16);
}
__device__ __forceinline__ float bf2f(unsigned short h) {
    return __uint_as_float(((unsigned)h) << 16);
}

// ws layout (unsigned short elements):
//   xrow [32][2048]        @ 0       x row-major bf16 (exact 0/1) - forward A-frags
//   frag [2048][64]        @ 65536   per p: [ tp_bf16(32 b) | x_bf16(32 b) ] - dw B-frags

__global__ __launch_bounds__(256) void stdp_prep(
    const float* __restrict__ x, const float* __restrict__ tpre,
    unsigned short* __restrict__ ws)
{
    int lin = blockIdx.x * 256 + threadIdx.x;    // 0..16383
    // phase A: xrow (row-major bf16), fully coalesced float4 in / 8B out
    int base = lin * 4;
    floatx4 xv = *(const floatx4*)(x + base);
    short4v xr;
#pragma unroll
    for (int j = 0; j < 4; ++j)
        xr[j] = (short)(__float_as_uint(xv[j]) >> 16);   // exact for {0,1}
    *(short4v*)(ws + base) = xr;

    // phase B: transposed frag rows; thread owns (p, 4 consecutive b) -> 8B stores
    int p  = lin >> 3;
    int b0 = (lin & 7) * 4;
    short4v tpv, xcv;
#pragma unroll
    for (int j = 0; j < 4; ++j) {
        float xx = x[(b0 + j) * PRE_ + p];
        float tt = tpre[(b0 + j) * PRE_ + p];
        tpv[j] = (short)f2bf(0.5f * tt + xx);            // tp, rounded bf16
        xcv[j] = (short)(__float_as_uint(xx) >> 16);
    }
    *(short4v*)(ws + 65536 + p * 64 + b0) = tpv;
    *(short4v*)(ws + 65536 + p * 64 + 32 + b0) = xcv;
}

// Fused: WG owns 8 q-rows. Wave-private W staging (k-slice == wave's K-split range
// == wave's dw p-range), forward split-bf16 MFMA -> spike, then dw with W from LDS.
__global__ __launch_bounds__(512) void stdp_fused(
    const float* __restrict__ W, const float* __restrict__ trace_post,
    const unsigned short* __restrict__ ws, float* __restrict__ out)
{
    __shared__ __align__(16) unsigned short Wh[QT * WPAD];   // 32.9 KB
    __shared__ __align__(16) unsigned short Wl[QT * WPAD];   // 32.9 KB
    __shared__ __align__(16) float red[8 * 2 * 4 * 64];      // 16 KB
    __shared__ __align__(16) unsigned short spnq[QT * 64];   // [q][ sp(32) | -tq(32) ]

    const int tid  = threadIdx.x;
    const int wave = tid >> 6, lane = tid & 63;
    const int quad = lane >> 4, l16 = lane & 15;
    const int q0   = blockIdx.x * QT;
    const int qb   = l16 & 7;
    const int kbase = wave * 256;     // wave's K-slice == its dw p-slice

    // prefetch trace_post for the post-barrier epilogue (waves 0,1 only)
    float tpr[4];
    if (wave < 2 && l16 < QT) {
#pragma unroll
        for (int r = 0; r < 4; ++r)
            tpr[r] = trace_post[(wave * 16 + quad * 4 + r) * POST_ + q0 + l16];
    }

    // ---- wave-private W staging: rows q0..q0+7, cols [kbase, kbase+256) ----
    floatx4 wv[8];
#pragma unroll
    for (int r = 0; r < 8; ++r)
        wv[r] = *(const floatx4*)(W + (q0 + r) * PRE_ + kbase + lane * 4);
#pragma unroll
    for (int r = 0; r < 8; ++r) {
        short4v hv, lv;
#pragma unroll
        for (int j = 0; j < 4; ++j) {
            unsigned short h = f2bf(wv[r][j]);
            hv[j] = (short)h;
            lv[j] = (short)f2bf(wv[r][j] - bf2f(h));
        }
        *(short4v*)&Wh[r * WPAD + kbase + lane * 4] = hv;
        *(short4v*)&Wl[r * WPAD + kbase + lane * 4] = lv;
    }

    // ---- forward: i[32 x 8] partial over wave's K-slice (no barrier needed:
    //      this wave wrote exactly the LDS it reads) ----
    const unsigned short* xrow = ws;
    floatx4 acc0 = {0.f, 0.f, 0.f, 0.f};
    floatx4 acc1 = {0.f, 0.f, 0.f, 0.f};
#pragma unroll
    for (int s = 0; s < 8; ++s) {
        int ko = kbase + s * 32 + quad * 8;
        short8 a0 = *(const short8*)(xrow + l16 * PRE_ + ko);
        short8 a1 = *(const short8*)(xrow + (16 + l16) * PRE_ + ko);
        short8 bh = *(const short8*)(Wh + qb * WPAD + ko);
        short8 bl = *(const short8*)(Wl + qb * WPAD + ko);
        acc0 = __builtin_amdgcn_mfma_f32_16x16x32_bf16(a0, bh, acc0, 0, 0, 0);
        acc0 = __builtin_amdgcn_mfma_f32_16x16x32_bf16(a0, bl, acc0, 0, 0, 0);
        acc1 = __builtin_amdgcn_mfma_f32_16x16x32_bf16(a1, bh, acc1, 0, 0, 0);
        acc1 = __builtin_amdgcn_mfma_f32_16x16x32_bf16(a1, bl, acc1, 0, 0, 0);
    }

    // prefetch first dw B-frags (independent of the barrier)
    const unsigned short* frag = ws + 65536;
    const int pbase = wave * 256;
    short8 ftp = *(const short8*)(frag + (pbase + l16) * 64 + quad * 8);
    short8 fx  = *(const short8*)(frag + (pbase + l16) * 64 + 32 + quad * 8);

    // ---- cross-wave K reduction ----
#pragma unroll
    for (int r = 0; r < 4; ++r) {
        red[((wave * 2 + 0) * 4 + r) * 64 + lane] = acc0[r];
        red[((wave * 2 + 1) * 4 + r) * 64 + lane] = acc1[r];
    }
    __syncthreads();

    if (wave < 2 && l16 < QT) {
        int q = q0 + l16;
#pragma unroll
        for (int r = 0; r < 4; ++r) {
            float s = 0.f;
#pragma unroll
            for (int w = 0; w < 8; ++w) s += red[((w * 2 + wave) * 4 + r) * 64 + lane];
            int b = wave * 16 + quad * 4 + r;
            float spike = (s >= 1.0f) ? 1.0f : 0.0f;
            out[b * POST_ + q] = spike;
            float ntq = -(0.5f * tpr[r] + spike);        // -tq, single rounded bf16
            spnq[l16 * 64 + b]      = f2bf(spike);
            spnq[l16 * 64 + 32 + b] = f2bf(ntq);
        }
    }
    __syncthreads();

    // ---- dw: wave's p-slice [pbase, pbase+256), K=32 -> 2 MFMAs/tile ----
    short8 fs  = *(const short8*)(spnq + qb * 64 + quad * 8);
    short8 fnq = *(const short8*)(spnq + qb * 64 + 32 + quad * 8);
    float* dw = out + B_ * POST_;

#pragma unroll 4
    for (int it = 0; it < 16; ++it) {
        // rotate-prefetch next B-frags (wraps harmlessly to it=0 at the end)
        int pn = (pbase + (((it + 1) & 15) * 16) + l16) * 64;
        short8 ntp = *(const short8*)(frag + pn + quad * 8);
        short8 nx  = *(const short8*)(frag + pn + 32 + quad * 8);

        floatx4 acc = {0.f, 0.f, 0.f, 0.f};
        acc = __builtin_amdgcn_mfma_f32_16x16x32_bf16(fs,  ftp, acc, 0, 0, 0);
        acc = __builtin_amdgcn_mfma_f32_16x16x32_bf16(fnq, fx,  acc, 0, 0, 0);

        int p = pbase + it * 16 + l16;
        if (quad < 2) {
#pragma unroll
            for (int r = 0; r < 4; ++r) {
                int qd = quad * 4 + r;
                float wvv = bf2f(Wh[qd * WPAD + p]) + bf2f(Wl[qd * WPAD + p]);
                wvv = fminf(fmaxf(wvv, -1.0f), 1.0f);
                dw[(q0 + qd) * PRE_ + p] = wvv * acc[r];
            }
        }
        ftp = ntp; fx = nx;
    }
}

extern "C" void kernel_launch(void* const* d_in, const int* in_sizes, int n_in,
                              void* d_out, int out_size, void* d_ws, size_t ws_size,
                              hipStream_t stream) {
    const float* x     = (const float*)d_in[0];
    const float* W     = (const float*)d_in[1];
    const float* tpre  = (const float*)d_in[2];
    const float* tpost = (const float*)d_in[3];
    float* out = (float*)d_out;
    unsigned short* ws = (unsigned short*)d_ws;

    hipLaunchKernelGGL(stdp_prep, dim3(64), dim3(256), 0, stream, x, tpre, ws);
    hipLaunchKernelGGL(stdp_fused, dim3(POST_ / QT), dim3(512), 0, stream,
                       W, tpost, ws, out);
}